// Round 16
// baseline (290.485 us; speedup 1.0000x reference)
//
#include <hip/hip_runtime.h>

// ---------- types ----------
typedef __attribute__((ext_vector_type(4))) int i32x4;

#define N_ROWS 3136
#define M_COLS 20000
#define KDIM   1536
#define NCT    157            // ceil(20000/128)
#define NRT    25             // ceil(3136/128)
#define NWG    (NCT * NRT)    // 3925
#define PPR    (NCT*9)        // 1413

#define QSCL   (4.0f / 127.0f)
#define QINV   (127.0f / 4.0f)
#define TWO_S2 (2.0f * QSCL * QSCL)

#define GLOAD_LDS16(g, l) __builtin_amdgcn_global_load_lds( \
    (const __attribute__((address_space(1))) unsigned int*)(g), \
    (__attribute__((address_space(3))) unsigned int*)(l), 16, 0, 0)

// sorted ascending insert: min(t[s], max(v, t[s-1])) == median(v,t[s-1],t[s])
// under the sorted invariant -> single v_med3_f32 per slot (HW-validated R7-R15).
__device__ inline void t9_insert(float (&t)[9], float v) {
    #pragma unroll
    for (int s = 8; s >= 1; --s)
        t[s] = __builtin_amdgcn_fmed3f(v, t[s-1], t[s]);   // uses OLD t[s-1]
    t[0] = fminf(t[0], v);
}

__device__ inline int q8(float x) {
    int q = (int)rintf(x * QINV);
    q = q > 127 ? 127 : q;
    q = q < -127 ? -127 : q;
    return q & 255;
}

// ---------- fused f32->i8 quantization + exact f32 row norms (wave per row) ----------
__global__ void cvt_norm_kernel(const float* __restrict__ emb,
                                const float* __restrict__ mb,
                                unsigned char* __restrict__ embq,
                                unsigned char* __restrict__ mbq,
                                float* __restrict__ x2, float* __restrict__ y2) {
    int lane = threadIdx.x & 63;
    int row = blockIdx.x * (blockDim.x >> 6) + (threadIdx.x >> 6);
    const float* src; unsigned char* dst; float* nrm; int r;
    if (row < M_COLS) { src = mb;  dst = mbq;  nrm = y2; r = row; }
    else              { src = emb; dst = embq; nrm = x2; r = row - M_COLS; }
    const float4* p = (const float4*)(src + (size_t)r * KDIM);
    int* q = (int*)(dst + (size_t)r * KDIM);
    float s = 0.f;
    #pragma unroll
    for (int i = 0; i < 6; ++i) {              // 384 float4 / 64 lanes
        float4 v = p[lane + i * 64];
        s += v.x*v.x + v.y*v.y + v.z*v.z + v.w*v.w;
        q[lane + i * 64] = q8(v.x) | (q8(v.y) << 8) | (q8(v.z) << 16) | (q8(v.w) << 24);
    }
    #pragma unroll
    for (int off = 32; off > 0; off >>= 1) s += __shfl_down(s, off);
    if (lane == 0) nrm[r] = s;
}

// ---------- fused distance GEMM + per-tile top-9 (i8, 128x128) ----------
// LDS-BW-relief variant: A operand loads GLOBAL->REG (L2-resident, double-buffered
// aCur/aNext), only B staged through LDS (gload_lds + bank swizzle). Cuts per-step
// LDS traffic 48KB -> 24KB (theory: per-CU LDS pipe was ~130% oversubscribed,
// explaining the R9/R13/R14 nulls). Issue order B-then-A so vmcnt(4) drains B only.
union SMem {
    unsigned char stg[2][8192];                          // B double-buffer only
    struct { float Ds[32 * 129]; float T9[8 * 32 * 9]; } epi;  // 25,728 B
};

#define STAGE_B(BUF, KT) do { \
    const int koff_ = (KT) * 64; \
    GLOAD_LDS16(pb[0] + koff_, sm.stg[BUF] + ldsoff[0]); \
    GLOAD_LDS16(pb[1] + koff_, sm.stg[BUF] + ldsoff[1]); \
} while (0)

#define KSTEP(CB, NB, AC, AN, KT, PF) do { \
    if (PF) { \
        STAGE_B(NB, (KT) + 1); \
        AN[0] = *(const i32x4*)(paf0 + ((KT) + 1) * 64); \
        AN[1] = *(const i32x4*)(paf1 + ((KT) + 1) * 64); \
        AN[2] = *(const i32x4*)(paf2 + ((KT) + 1) * 64); \
        AN[3] = *(const i32x4*)(paf3 + ((KT) + 1) * 64); \
    } \
    i32x4 bfr[4]; \
    _Pragma("unroll") \
    for (int ni = 0; ni < 4; ++ni) \
        bfr[ni] = *(const i32x4*)(sm.stg[CB] + (wc + ni * 16 + l15) * 64 + kbs); \
    _Pragma("unroll") \
    for (int mi = 0; mi < 4; ++mi) \
        _Pragma("unroll") \
        for (int ni = 0; ni < 4; ++ni) \
            acc[mi][ni] = __builtin_amdgcn_mfma_i32_16x16x64_i8(AC[mi], bfr[ni], acc[mi][ni], 0, 0, 0); \
    if (PF) { asm volatile("s_waitcnt vmcnt(4)" ::: "memory"); } \
    else    { asm volatile("s_waitcnt vmcnt(0)" ::: "memory"); } \
    __builtin_amdgcn_s_barrier(); \
} while (0)

__global__ __launch_bounds__(256, 3) void dist_topk_kernel(
    const unsigned char* __restrict__ Aq,    // [3136][1536] i8
    const unsigned char* __restrict__ Bq,    // [20000][1536] i8
    const float* __restrict__ x2, const float* __restrict__ y2,
    float* __restrict__ partials)
{
    __shared__ __align__(16) SMem sm;

    const int tid = threadIdx.x;
    const int wave = tid >> 6, lane = tid & 63;

    // bijective chunked XCD swizzle (m204 form; 3925 % 8 = 5), ct-major:
    // 25 consecutive wg (same XCD) share one B-tile (L2-resident; proven R10/R11).
    int orig = blockIdx.x;
    int xcd = orig & 7, li = orig >> 3;
    const int qc = NWG / 8, rc = NWG % 8;     // 490, 5
    int wg = (xcd < rc ? xcd * (qc + 1) : rc * (qc + 1) + (xcd - rc) * qc) + li;
    const int ct = wg / NRT, rt = wg % NRT;
    const int rowBase = rt * 128, colBase = ct * 128;

    // B staging: 2 x 16B chunks per thread; global k-chunk pre-swizzled
    // (bank-slot XOR with row bits 1-2) so linear LDS dest yields swizzled layout.
    const unsigned char* pb[2];
    int ldsoff[2];
    #pragma unroll
    for (int i = 0; i < 2; ++i) {
        int flat = i * 256 + tid;        // 0..511 chunks of the 8 KB B-tile
        int r = flat >> 2;               // tile row 0..127
        int kk = (((flat & 3) ^ ((flat >> 3) & 3))) * 16;   // swizzled k-chunk
        int bc = colBase + r; bc = bc < M_COLS ? bc : M_COLS - 1;
        pb[i] = Bq + (size_t)bc * KDIM + kk;
        ldsoff[i] = flat * 16;           // bytes, lane-linear (legal gload_lds dest)
    }

    const int l15 = lane & 15;
    const int kb = (lane >> 4) * 16;                 // fragment k-base (bytes)
    const int kbs = kb ^ (((l15 >> 1) & 3) << 4);    // swizzled B slot
    const int g4 = (lane >> 4) * 4;                  // C fragment row-base
    const int wr = (wave >> 1) * 64;
    const int wc = (wave & 1) * 64;

    // A fragment base pointers (global, per-lane; wave reads 16 rows x 64 B/step)
    auto aptr = [&](int mi) {
        int r = rowBase + wr + mi * 16 + l15;
        r = r < N_ROWS ? r : N_ROWS - 1;
        return Aq + (size_t)r * KDIM + kb;
    };
    const unsigned char* paf0 = aptr(0);
    const unsigned char* paf1 = aptr(1);
    const unsigned char* paf2 = aptr(2);
    const unsigned char* paf3 = aptr(3);

    i32x4 acc[4][4] = {};
    i32x4 a0[4], a1[4];

    // prologue: B(0) into buf 0 + A(0) into regs; drain B before first ds_read
    STAGE_B(0, 0);
    a0[0] = *(const i32x4*)(paf0);
    a0[1] = *(const i32x4*)(paf1);
    a0[2] = *(const i32x4*)(paf2);
    a0[3] = *(const i32x4*)(paf3);
    asm volatile("s_waitcnt vmcnt(4)" ::: "memory");   // B(0) done; A(0) via reg deps
    __builtin_amdgcn_s_barrier();

    // 24 K-steps, unrolled x2 for static buffer/reg indices
    #pragma unroll 1
    for (int kt = 0; kt < 24; kt += 2) {
        KSTEP(0, 1, a0, a1, kt, 1);
        KSTEP(1, 0, a1, a0, kt + 1, (kt + 2) < 24);
    }

    // ---- epilogue: 4 passes of 32 rows (R12/R15-proven layout) ----
    int ncols = M_COLS - colBase; ncols = ncols < 128 ? ncols : 128;

    #pragma unroll
    for (int p = 0; p < 4; ++p) {
        __syncthreads();                 // prev pass reads done before Ds overwrite
        if ((wave >> 1) == (p >> 1)) {   // 2 waves own this 32-row slab
            const int mi0 = (p & 1) * 2;
            #pragma unroll
            for (int ni = 0; ni < 4; ++ni) {
                int c = wc + ni * 16 + l15;
                int gc = colBase + c;
                float yv = y2[gc < M_COLS ? gc : M_COLS - 1];
                #pragma unroll
                for (int mh = 0; mh < 2; ++mh) {
                    #pragma unroll
                    for (int j = 0; j < 4; ++j) {
                        int rloc = mh * 16 + g4 + j;          // 0..31
                        int gr = rowBase + p * 32 + rloc;
                        float xv = x2[gr < N_ROWS ? gr : N_ROWS - 1];
                        sm.epi.Ds[rloc * 129 + c] = xv + yv - TWO_S2 * (float)acc[mi0 + mh][ni][j];
                    }
                }
            }
        }
        __syncthreads();
        // 8-way column-split scan: thread (q8g, r) scans cols [q8g*16, q8g*16+16)
        int r = tid & 31, q8g = tid >> 5;
        int grow = rowBase + p * 32 + r;
        float t9[9];
        #pragma unroll
        for (int s = 0; s < 9; ++s) t9[s] = 3.4e38f;
        int cs = q8g * 16;
        int ce = (cs + 16 < ncols) ? cs + 16 : ncols;
        for (int c = cs; c < ce; ++c) t9_insert(t9, sm.epi.Ds[r * 129 + c]);
        #pragma unroll
        for (int s = 0; s < 9; ++s) sm.epi.T9[(q8g * 32 + r) * 9 + s] = t9[s];
        __syncthreads();
        if (q8g < 4) {                   // pair-merge round: 4 lists/row remain
            #pragma unroll
            for (int s = 0; s < 9; ++s)
                t9_insert(t9, sm.epi.T9[((q8g + 4) * 32 + r) * 9 + s]);
            #pragma unroll
            for (int s = 0; s < 9; ++s) sm.epi.T9[(q8g * 32 + r) * 9 + s] = t9[s];
        }
        __syncthreads();
        if (q8g == 0 && grow < N_ROWS) { // final 3-list merge + store
            #pragma unroll
            for (int qq = 1; qq < 4; ++qq)
                #pragma unroll
                for (int s = 0; s < 9; ++s)
                    t9_insert(t9, sm.epi.T9[(qq * 32 + r) * 9 + s]);
            float* dst = partials + (size_t)grow * PPR + ct * 9;
            #pragma unroll
            for (int s = 0; s < 9; ++s) dst[s] = t9[s];
        }
    }
}

// ---------- merge 157 sorted-9 lists per row -> final top-9 (one wave per row) ----------
__global__ void merge_topk_kernel(const float* __restrict__ partials,
                                  float* __restrict__ scores) {
    int lane = threadIdx.x & 63;
    int row = blockIdx.x * 4 + (threadIdx.x >> 6);   // 4 waves/block, 784 blocks
    const float* p = partials + (size_t)row * PPR;
    float t9[9];
    #pragma unroll
    for (int s = 0; s < 9; ++s) t9[s] = 3.4e38f;
    for (int i = lane; i < PPR; i += 64) {           // coalesced strided scan
        float v = p[i];
        if (v < t9[8]) t9_insert(t9, v);
    }
    #pragma unroll
    for (int off = 32; off > 0; off >>= 1) {
        float o[9];
        #pragma unroll
        for (int s = 0; s < 9; ++s) o[s] = __shfl_xor(t9[s], off);
        #pragma unroll
        for (int s = 0; s < 9; ++s)
            if (o[s] < t9[8]) t9_insert(t9, o[s]);
    }
    if (lane == 0) {
        #pragma unroll
        for (int s = 0; s < 9; ++s)
            scores[row * 9 + s] = sqrtf(fmaxf(t9[s], 0.f));
    }
}

// ---------- gaussian blur (fused with x8 nearest upsample), sigma=4, K=33 ----------
__global__ void blur_h_kernel(const float* __restrict__ scores, float* __restrict__ tH) {
    int idx = blockIdx.x * blockDim.x + threadIdx.x;
    if (idx >= 4 * 224 * 28) return;
    int pw = idx % 28, y = (idx / 28) % 224, b = idx / (28 * 224);
    float acc = 0.f, gsum = 0.f;
    #pragma unroll
    for (int k = 0; k < 33; ++k) {
        float xk = (float)(k - 16);
        float w = expf(-xk * xk * (1.0f / 32.0f));
        gsum += w;
        int yy = y - 16 + k;
        yy = yy < 0 ? -yy : yy;            // reflect
        yy = yy > 223 ? 446 - yy : yy;
        acc += w * scores[(size_t)(b * 784 + (yy >> 3) * 28 + pw) * 9];
    }
    tH[idx] = acc / gsum;
}

__global__ void blur_w_kernel(const float* __restrict__ tH, float* __restrict__ out) {
    int idx = blockIdx.x * blockDim.x + threadIdx.x;
    if (idx >= 4 * 224 * 224) return;
    int x = idx % 224, y = (idx / 224) % 224, b = idx / (224 * 224);
    float acc = 0.f, gsum = 0.f;
    #pragma unroll
    for (int k = 0; k < 33; ++k) {
        float xk = (float)(k - 16);
        float w = expf(-xk * xk * (1.0f / 32.0f));
        gsum += w;
        int xx = x - 16 + k;
        xx = xx < 0 ? -xx : xx;
        xx = xx > 223 ? 446 - xx : xx;
        acc += w * tH[(b * 224 + y) * 28 + (xx >> 3)];
    }
    out[idx] = acc / gsum;
}

// ---------- anomaly score ----------
__global__ void score_kernel(const float* __restrict__ scores, float* __restrict__ out) {
    __shared__ float vmax[256];
    __shared__ int   vidx[256];
    int tid = threadIdx.x;
    float best = -3.4e38f; int bi = 0x7fffffff;
    for (int r = tid; r < N_ROWS; r += 256) {
        float v = scores[r * 9];
        if (v > best) { best = v; bi = r; }
    }
    vmax[tid] = best; vidx[tid] = bi;
    __syncthreads();
    for (int s = 128; s > 0; s >>= 1) {
        if (tid < s) {
            if (vmax[tid + s] > vmax[tid] ||
                (vmax[tid + s] == vmax[tid] && vidx[tid + s] < vidx[tid])) {
                vmax[tid] = vmax[tid + s]; vidx[tid] = vidx[tid + s];
            }
        }
        __syncthreads();
    }
    if (tid == 0) {
        int idx = vidx[0];
        float es = 0.f, em = -3.4e38f;
        #pragma unroll
        for (int s = 0; s < 9; ++s) {
            float e = expf(scores[idx * 9 + s]);
            es += e; em = fmaxf(em, e);
        }
        out[4 * 224 * 224] = (1.0f - em / es) * vmax[0];
    }
}

// ---------- launch ----------
extern "C" void kernel_launch(void* const* d_in, const int* in_sizes, int n_in,
                              void* d_out, int out_size, void* d_ws, size_t ws_size,
                              hipStream_t stream) {
    const float* emb = (const float*)d_in[0];   // [3136,1536]
    const float* mb  = (const float*)d_in[1];   // [20000,1536]
    float* out = (float*)d_out;                 // 200704 amap + 1 score
    char* ws = (char*)d_ws;

    unsigned char* mbq      = (unsigned char*)(ws);               // 30,720,000 B
    unsigned char* embq     = (unsigned char*)(ws + 30720000);    //  4,816,896 B
    float*         x2       = (float*)(ws + 35536896);            //     12,544 B
    float*         y2       = (float*)(ws + 35549440);            //     80,000 B
    float*         partials = (float*)(ws + 35629440);            // 17,724,672 B
    float*         scores   = (float*)(ws + 53354112);            //    112,896 B
    float*         tH       = (float*)(ws + 53467008);            //    100,352 B

    cvt_norm_kernel<<<(M_COLS + N_ROWS) / 4, 256, 0, stream>>>(emb, mb, embq, mbq, x2, y2);
    dist_topk_kernel<<<NWG, 256, 0, stream>>>(embq, mbq, x2, y2, partials);
    merge_topk_kernel<<<N_ROWS / 4, 256, 0, stream>>>(partials, scores);
    blur_h_kernel<<<(4 * 224 * 28 + 255) / 256, 256, 0, stream>>>(scores, tH);
    blur_w_kernel<<<(4 * 224 * 224 + 255) / 256, 256, 0, stream>>>(tH, out);
    score_kernel<<<1, 256, 0, stream>>>(scores, out);
}

// Round 17
// 208.707 us; speedup vs baseline: 1.3918x; 1.3918x over previous
//
#include <hip/hip_runtime.h>

// ---------- types ----------
typedef __attribute__((ext_vector_type(4))) int i32x4;

#define N_ROWS 3136
#define M_COLS 20000
#define KDIM   1536
#define NCT    157            // ceil(20000/128)
#define NRT    25             // ceil(3136/128)
#define NWG    (NCT * NRT)    // 3925
#define PPR    (NCT*9)        // 1413

#define QSCL   (4.0f / 127.0f)
#define QINV   (127.0f / 4.0f)
#define TWO_S2 (2.0f * QSCL * QSCL)

#define GLOAD_LDS16(g, l) __builtin_amdgcn_global_load_lds( \
    (const __attribute__((address_space(1))) unsigned int*)(g), \
    (__attribute__((address_space(3))) unsigned int*)(l), 16, 0, 0)

// sorted ascending insert: min(t[s], max(v, t[s-1])) == median(v,t[s-1],t[s])
// under the sorted invariant -> single v_med3_f32 per slot (HW-validated R7-R15).
__device__ inline void t9_insert(float (&t)[9], float v) {
    #pragma unroll
    for (int s = 8; s >= 1; --s)
        t[s] = __builtin_amdgcn_fmed3f(v, t[s-1], t[s]);   // uses OLD t[s-1]
    t[0] = fminf(t[0], v);
}

__device__ inline int q8(float x) {
    int q = (int)rintf(x * QINV);
    q = q > 127 ? 127 : q;
    q = q < -127 ? -127 : q;
    return q & 255;
}

// ---------- fused f32->i8 quantization + exact f32 row norms (wave per row) ----------
__global__ void cvt_norm_kernel(const float* __restrict__ emb,
                                const float* __restrict__ mb,
                                unsigned char* __restrict__ embq,
                                unsigned char* __restrict__ mbq,
                                float* __restrict__ x2, float* __restrict__ y2) {
    int lane = threadIdx.x & 63;
    int row = blockIdx.x * (blockDim.x >> 6) + (threadIdx.x >> 6);
    const float* src; unsigned char* dst; float* nrm; int r;
    if (row < M_COLS) { src = mb;  dst = mbq;  nrm = y2; r = row; }
    else              { src = emb; dst = embq; nrm = x2; r = row - M_COLS; }
    const float4* p = (const float4*)(src + (size_t)r * KDIM);
    int* q = (int*)(dst + (size_t)r * KDIM);
    float s = 0.f;
    #pragma unroll
    for (int i = 0; i < 6; ++i) {              // 384 float4 / 64 lanes
        float4 v = p[lane + i * 64];
        s += v.x*v.x + v.y*v.y + v.z*v.z + v.w*v.w;
        q[lane + i * 64] = q8(v.x) | (q8(v.y) << 8) | (q8(v.z) << 16) | (q8(v.w) << 24);
    }
    #pragma unroll
    for (int off = 32; off > 0; off >>= 1) s += __shfl_down(s, off);
    if (lane == 0) nrm[r] = s;
}

// ---------- fused distance GEMM + per-tile top-9 (i8, 128x128, 2-phase dbuf) ----------
// Best-known config (R15, 209.5 us total): 256 thr, 60 VGPR + 64 AGPR, 32 KB LDS,
// 2-phase double-buffer, k-chunk bank swizzle, ct-major chunked XCD swizzle, med3
// top-9. Structural ceiling: six escape routes measured null/negative (R9 conflicts,
// R11 L2-residency, R13 occupancy, R14 vmcnt-depth, R3-5 8-phase, R16 A-off-LDS);
// pinned at ~27% of i8 peak = the measured 2-phase schedule ceiling (m230/m233).
union SMem {
    unsigned char stg[2][16384];                         // 2 x (A 8KB | B 8KB)
    struct { float Ds[32 * 129]; float T9[8 * 32 * 9]; } epi;  // 25,728 B
};

#define STAGE(BUF, KT) do { \
    const int koff_ = (KT) * 64; \
    GLOAD_LDS16(pa[0] + koff_, sm.stg[BUF] + ldsoff[0]); \
    GLOAD_LDS16(pa[1] + koff_, sm.stg[BUF] + ldsoff[1]); \
    GLOAD_LDS16(pb[0] + koff_, sm.stg[BUF] + 8192 + ldsoff[0]); \
    GLOAD_LDS16(pb[1] + koff_, sm.stg[BUF] + 8192 + ldsoff[1]); \
} while (0)

#define KSTEP(CB, NB, KT, PF) do { \
    if (PF) STAGE(NB, (KT) + 1); \
    i32x4 af[4], bfr[4]; \
    _Pragma("unroll") \
    for (int mi = 0; mi < 4; ++mi) \
        af[mi] = *(const i32x4*)(sm.stg[CB] + (wr + mi * 16 + l15) * 64 + kbs); \
    _Pragma("unroll") \
    for (int ni = 0; ni < 4; ++ni) \
        bfr[ni] = *(const i32x4*)(sm.stg[CB] + 8192 + (wc + ni * 16 + l15) * 64 + kbs); \
    _Pragma("unroll") \
    for (int mi = 0; mi < 4; ++mi) \
        _Pragma("unroll") \
        for (int ni = 0; ni < 4; ++ni) \
            acc[mi][ni] = __builtin_amdgcn_mfma_i32_16x16x64_i8(af[mi], bfr[ni], acc[mi][ni], 0, 0, 0); \
    asm volatile("s_waitcnt vmcnt(0)" ::: "memory"); \
    __builtin_amdgcn_s_barrier(); \
} while (0)

__global__ __launch_bounds__(256, 4) void dist_topk_kernel(
    const unsigned char* __restrict__ Aq,    // [3136][1536] i8
    const unsigned char* __restrict__ Bq,    // [20000][1536] i8
    const float* __restrict__ x2, const float* __restrict__ y2,
    float* __restrict__ partials)
{
    __shared__ __align__(16) SMem sm;

    const int tid = threadIdx.x;
    const int wave = tid >> 6, lane = tid & 63;

    // bijective chunked XCD swizzle (m204 form; 3925 % 8 = 5), ct-major:
    // 25 consecutive wg (same XCD) share one B-tile (L2-resident; FETCH 419->123 MB).
    int orig = blockIdx.x;
    int xcd = orig & 7, li = orig >> 3;
    const int qc = NWG / 8, rc = NWG % 8;     // 490, 5
    int wg = (xcd < rc ? xcd * (qc + 1) : rc * (qc + 1) + (xcd - rc) * qc) + li;
    const int ct = wg / NRT, rt = wg % NRT;
    const int rowBase = rt * 128, colBase = ct * 128;

    // staging: 2 x 16B chunks per thread per matrix; global k-chunk pre-swizzled
    // (bank-slot XOR with row bits 1-2) so linear LDS dest yields swizzled layout.
    const unsigned char* pa[2];
    const unsigned char* pb[2];
    int ldsoff[2];
    #pragma unroll
    for (int i = 0; i < 2; ++i) {
        int flat = i * 256 + tid;        // 0..511
        int r = flat >> 2;               // tile row 0..127
        int kk = (((flat & 3) ^ ((flat >> 3) & 3))) * 16;   // swizzled k-chunk
        int ar = rowBase + r; ar = ar < N_ROWS ? ar : N_ROWS - 1;   // clamp
        int bc = colBase + r; bc = bc < M_COLS ? bc : M_COLS - 1;
        pa[i] = Aq + (size_t)ar * KDIM + kk;
        pb[i] = Bq + (size_t)bc * KDIM + kk;
        ldsoff[i] = flat * 16;           // bytes, lane-linear (legal gload_lds dest)
    }

    const int l15 = lane & 15;
    const int kb = (lane >> 4) * 16;                 // fragment k-base (bytes)
    const int kbs = kb ^ (((l15 >> 1) & 3) << 4);    // swizzled slot (mi/ni-invariant)
    const int g4 = (lane >> 4) * 4;                  // C fragment row-base
    const int wr = (wave >> 1) * 64;
    const int wc = (wave & 1) * 64;

    i32x4 acc[4][4] = {};

    // prologue: tile 0 into buf 0, full drain
    STAGE(0, 0);
    asm volatile("s_waitcnt vmcnt(0)" ::: "memory");
    __builtin_amdgcn_s_barrier();

    // 24 K-steps, unrolled x2 for static buffer indices
    #pragma unroll 1
    for (int kt = 0; kt < 24; kt += 2) {
        KSTEP(0, 1, kt, 1);
        KSTEP(1, 0, kt + 1, (kt + 2) < 24);
    }

    // ---- epilogue: 4 passes of 32 rows (32 KB LDS union) ----
    int ncols = M_COLS - colBase; ncols = ncols < 128 ? ncols : 128;

    #pragma unroll
    for (int p = 0; p < 4; ++p) {
        __syncthreads();                 // prev pass reads done before Ds overwrite
        if ((wave >> 1) == (p >> 1)) {   // 2 waves own this 32-row slab
            const int mi0 = (p & 1) * 2;
            #pragma unroll
            for (int ni = 0; ni < 4; ++ni) {
                int c = wc + ni * 16 + l15;
                int gc = colBase + c;
                float yv = y2[gc < M_COLS ? gc : M_COLS - 1];
                #pragma unroll
                for (int mh = 0; mh < 2; ++mh) {
                    #pragma unroll
                    for (int j = 0; j < 4; ++j) {
                        int rloc = mh * 16 + g4 + j;          // 0..31
                        int gr = rowBase + p * 32 + rloc;
                        float xv = x2[gr < N_ROWS ? gr : N_ROWS - 1];
                        sm.epi.Ds[rloc * 129 + c] = xv + yv - TWO_S2 * (float)acc[mi0 + mh][ni][j];
                    }
                }
            }
        }
        __syncthreads();
        // 8-way column-split scan: thread (q8g, r) scans cols [q8g*16, q8g*16+16)
        int r = tid & 31, q8g = tid >> 5;
        int grow = rowBase + p * 32 + r;
        float t9[9];
        #pragma unroll
        for (int s = 0; s < 9; ++s) t9[s] = 3.4e38f;
        int cs = q8g * 16;
        int ce = (cs + 16 < ncols) ? cs + 16 : ncols;
        for (int c = cs; c < ce; ++c) t9_insert(t9, sm.epi.Ds[r * 129 + c]);
        #pragma unroll
        for (int s = 0; s < 9; ++s) sm.epi.T9[(q8g * 32 + r) * 9 + s] = t9[s];
        __syncthreads();
        if (q8g < 4) {                   // pair-merge round: 4 lists/row remain
            #pragma unroll
            for (int s = 0; s < 9; ++s)
                t9_insert(t9, sm.epi.T9[((q8g + 4) * 32 + r) * 9 + s]);
            #pragma unroll
            for (int s = 0; s < 9; ++s) sm.epi.T9[(q8g * 32 + r) * 9 + s] = t9[s];
        }
        __syncthreads();
        if (q8g == 0 && grow < N_ROWS) { // final 3-list merge + store
            #pragma unroll
            for (int qq = 1; qq < 4; ++qq)
                #pragma unroll
                for (int s = 0; s < 9; ++s)
                    t9_insert(t9, sm.epi.T9[(qq * 32 + r) * 9 + s]);
            float* dst = partials + (size_t)grow * PPR + ct * 9;
            #pragma unroll
            for (int s = 0; s < 9; ++s) dst[s] = t9[s];
        }
    }
}

// ---------- merge 157 sorted-9 lists per row -> final top-9 (one wave per row) ----------
__global__ void merge_topk_kernel(const float* __restrict__ partials,
                                  float* __restrict__ scores) {
    int lane = threadIdx.x & 63;
    int row = blockIdx.x * 4 + (threadIdx.x >> 6);   // 4 waves/block, 784 blocks
    const float* p = partials + (size_t)row * PPR;
    float t9[9];
    #pragma unroll
    for (int s = 0; s < 9; ++s) t9[s] = 3.4e38f;
    for (int i = lane; i < PPR; i += 64) {           // coalesced strided scan
        float v = p[i];
        if (v < t9[8]) t9_insert(t9, v);
    }
    #pragma unroll
    for (int off = 32; off > 0; off >>= 1) {
        float o[9];
        #pragma unroll
        for (int s = 0; s < 9; ++s) o[s] = __shfl_xor(t9[s], off);
        #pragma unroll
        for (int s = 0; s < 9; ++s)
            if (o[s] < t9[8]) t9_insert(t9, o[s]);
    }
    if (lane == 0) {
        #pragma unroll
        for (int s = 0; s < 9; ++s)
            scores[row * 9 + s] = sqrtf(fmaxf(t9[s], 0.f));
    }
}

// ---------- gaussian blur (fused with x8 nearest upsample), sigma=4, K=33 ----------
__global__ void blur_h_kernel(const float* __restrict__ scores, float* __restrict__ tH) {
    int idx = blockIdx.x * blockDim.x + threadIdx.x;
    if (idx >= 4 * 224 * 28) return;
    int pw = idx % 28, y = (idx / 28) % 224, b = idx / (28 * 224);
    float acc = 0.f, gsum = 0.f;
    #pragma unroll
    for (int k = 0; k < 33; ++k) {
        float xk = (float)(k - 16);
        float w = expf(-xk * xk * (1.0f / 32.0f));
        gsum += w;
        int yy = y - 16 + k;
        yy = yy < 0 ? -yy : yy;            // reflect
        yy = yy > 223 ? 446 - yy : yy;
        acc += w * scores[(size_t)(b * 784 + (yy >> 3) * 28 + pw) * 9];
    }
    tH[idx] = acc / gsum;
}

__global__ void blur_w_kernel(const float* __restrict__ tH, float* __restrict__ out) {
    int idx = blockIdx.x * blockDim.x + threadIdx.x;
    if (idx >= 4 * 224 * 224) return;
    int x = idx % 224, y = (idx / 224) % 224, b = idx / (224 * 224);
    float acc = 0.f, gsum = 0.f;
    #pragma unroll
    for (int k = 0; k < 33; ++k) {
        float xk = (float)(k - 16);
        float w = expf(-xk * xk * (1.0f / 32.0f));
        gsum += w;
        int xx = x - 16 + k;
        xx = xx < 0 ? -xx : xx;
        xx = xx > 223 ? 446 - xx : xx;
        acc += w * tH[(b * 224 + y) * 28 + (xx >> 3)];
    }
    out[idx] = acc / gsum;
}

// ---------- anomaly score ----------
__global__ void score_kernel(const float* __restrict__ scores, float* __restrict__ out) {
    __shared__ float vmax[256];
    __shared__ int   vidx[256];
    int tid = threadIdx.x;
    float best = -3.4e38f; int bi = 0x7fffffff;
    for (int r = tid; r < N_ROWS; r += 256) {
        float v = scores[r * 9];
        if (v > best) { best = v; bi = r; }
    }
    vmax[tid] = best; vidx[tid] = bi;
    __syncthreads();
    for (int s = 128; s > 0; s >>= 1) {
        if (tid < s) {
            if (vmax[tid + s] > vmax[tid] ||
                (vmax[tid + s] == vmax[tid] && vidx[tid + s] < vidx[tid])) {
                vmax[tid] = vmax[tid + s]; vidx[tid] = vidx[tid + s];
            }
        }
        __syncthreads();
    }
    if (tid == 0) {
        int idx = vidx[0];
        float es = 0.f, em = -3.4e38f;
        #pragma unroll
        for (int s = 0; s < 9; ++s) {
            float e = expf(scores[idx * 9 + s]);
            es += e; em = fmaxf(em, e);
        }
        out[4 * 224 * 224] = (1.0f - em / es) * vmax[0];
    }
}

// ---------- launch ----------
extern "C" void kernel_launch(void* const* d_in, const int* in_sizes, int n_in,
                              void* d_out, int out_size, void* d_ws, size_t ws_size,
                              hipStream_t stream) {
    const float* emb = (const float*)d_in[0];   // [3136,1536]
    const float* mb  = (const float*)d_in[1];   // [20000,1536]
    float* out = (float*)d_out;                 // 200704 amap + 1 score
    char* ws = (char*)d_ws;

    unsigned char* mbq      = (unsigned char*)(ws);               // 30,720,000 B
    unsigned char* embq     = (unsigned char*)(ws + 30720000);    //  4,816,896 B
    float*         x2       = (float*)(ws + 35536896);            //     12,544 B
    float*         y2       = (float*)(ws + 35549440);            //     80,000 B
    float*         partials = (float*)(ws + 35629440);            // 17,724,672 B
    float*         scores   = (float*)(ws + 53354112);            //    112,896 B
    float*         tH       = (float*)(ws + 53467008);            //    100,352 B

    cvt_norm_kernel<<<(M_COLS + N_ROWS) / 4, 256, 0, stream>>>(emb, mb, embq, mbq, x2, y2);
    dist_topk_kernel<<<NWG, 256, 0, stream>>>(embq, mbq, x2, y2, partials);
    merge_topk_kernel<<<N_ROWS / 4, 256, 0, stream>>>(partials, scores);
    blur_h_kernel<<<(4 * 224 * 28 + 255) / 256, 256, 0, stream>>>(scores, tH);
    blur_w_kernel<<<(4 * 224 * 224 + 255) / 256, 256, 0, stream>>>(tH, out);
    score_kernel<<<1, 256, 0, stream>>>(scores, out);
}